// Round 2
// baseline (168.571 us; speedup 1.0000x reference)
//
#include <hip/hip_runtime.h>

// y = (x_f - x_i)^T (W @ x_i)  — scalar output.
// HBM-bound on W (256 MiB read once). One wave per row, float4 loads.
// Fused: last-arriving block reduces the 2048 partials (device-scope
// atomics + fences for cross-XCD visibility). Counter in d_ws is zeroed
// by a 4-byte memset node each call (d_ws is poisoned once, never re-poisoned).

#define NDIM 8192
#define THREADS 256
#define WAVES_PER_BLOCK 4
#define BLOCKS (NDIM / WAVES_PER_BLOCK)   // 2048

__global__ __launch_bounds__(THREADS) void dyn_fused_kernel(
    const float* __restrict__ W,
    const float* __restrict__ x_i,
    const float* __restrict__ x_f,
    float* __restrict__ partial,
    unsigned int* __restrict__ counter,
    float* __restrict__ out) {
  const int wave = threadIdx.x >> 6;   // 0..3
  const int lane = threadIdx.x & 63;
  const int row = blockIdx.x * WAVES_PER_BLOCK + wave;

  const float4* __restrict__ Wrow =
      reinterpret_cast<const float4*>(W + (size_t)row * NDIM);
  const float4* __restrict__ X = reinterpret_cast<const float4*>(x_i);

  float acc = 0.0f;
  // NDIM/4 float4 per row = 2048; /64 lanes = 32 iterations.
#pragma unroll 4
  for (int it = 0; it < (NDIM / 4) / 64; ++it) {
    const float4 w = Wrow[it * 64 + lane];
    const float4 x = X[it * 64 + lane];
    acc = fmaf(w.x, x.x, acc);
    acc = fmaf(w.y, x.y, acc);
    acc = fmaf(w.z, x.z, acc);
    acc = fmaf(w.w, x.w, acc);
  }

  // wave (64-lane) butterfly reduction
#pragma unroll
  for (int off = 32; off > 0; off >>= 1) acc += __shfl_xor(acc, off, 64);

  __shared__ float wsum[WAVES_PER_BLOCK];
  __shared__ int is_last;
  if (lane == 0) wsum[wave] = acc * (x_f[row] - x_i[row]);
  __syncthreads();

  if (threadIdx.x == 0) {
    const float block_sum = (wsum[0] + wsum[1]) + (wsum[2] + wsum[3]);
    // Device-scope release store so the last block (possibly another XCD)
    // observes it after acquiring the ticket.
    __hip_atomic_store(&partial[blockIdx.x], block_sum, __ATOMIC_RELEASE,
                       __HIP_MEMORY_SCOPE_AGENT);
    const unsigned ticket = __hip_atomic_fetch_add(
        counter, 1u, __ATOMIC_ACQ_REL, __HIP_MEMORY_SCOPE_AGENT);
    is_last = (ticket == (unsigned)(gridDim.x - 1)) ? 1 : 0;
  }
  __syncthreads();

  if (is_last) {
    __threadfence();  // acquire: invalidate caches so partials are fresh
    float r = 0.0f;
    for (int i = threadIdx.x; i < BLOCKS; i += THREADS)
      r += __hip_atomic_load(&partial[i], __ATOMIC_RELAXED,
                             __HIP_MEMORY_SCOPE_AGENT);
#pragma unroll
    for (int off = 32; off > 0; off >>= 1) r += __shfl_xor(r, off, 64);
    __shared__ float fsum[WAVES_PER_BLOCK];
    if (lane == 0) fsum[wave] = r;
    __syncthreads();
    if (threadIdx.x == 0)
      out[0] = (fsum[0] + fsum[1]) + (fsum[2] + fsum[3]);
  }
}

extern "C" void kernel_launch(void* const* d_in, const int* in_sizes, int n_in,
                              void* d_out, int out_size, void* d_ws, size_t ws_size,
                              hipStream_t stream) {
  const float* x_i = (const float*)d_in[0];
  const float* x_f = (const float*)d_in[1];
  const float* W   = (const float*)d_in[2];
  // d_in[3] = t (numerically unused), d_in[4] = arg (unused)

  float* partial = (float*)d_ws;                          // 8 KiB
  unsigned int* counter = (unsigned int*)((char*)d_ws + BLOCKS * sizeof(float));
  float* out = (float*)d_out;

  // d_ws is poisoned to 0xAA once and never re-poisoned; zero the ticket
  // counter every call (graph-capturable memset node).
  hipMemsetAsync(counter, 0, sizeof(unsigned int), stream);

  dyn_fused_kernel<<<BLOCKS, THREADS, 0, stream>>>(W, x_i, x_f, partial,
                                                   counter, out);
}

// Round 3
// 54.296 us; speedup vs baseline: 3.1046x; 3.1046x over previous
//
#include <hip/hip_runtime.h>

// y = (x_f - x_i)^T (W @ x_i)  — scalar output.
// HBM/fabric-bound on W (256 MiB read once; ~half L3-resident across replays).
// One wave per row, float4 loads. Final reduction: one RELAXED device-scope
// atomicAdd per block (no fences — R2 showed agent-scope release/acquire per
// block triggers L2 cache-maintenance and a 6x slowdown). d_out zeroed by a
// 4-byte memset node each call (harness poisons once, validates after timing).

#define NDIM 8192
#define THREADS 256
#define WAVES_PER_BLOCK 4
#define BLOCKS (NDIM / WAVES_PER_BLOCK)   // 2048

__global__ __launch_bounds__(THREADS) void dyn_fused_kernel(
    const float* __restrict__ W,
    const float* __restrict__ x_i,
    const float* __restrict__ x_f,
    float* __restrict__ out) {
  const int wave = threadIdx.x >> 6;   // 0..3
  const int lane = threadIdx.x & 63;
  const int row = blockIdx.x * WAVES_PER_BLOCK + wave;

  const float4* __restrict__ Wrow =
      reinterpret_cast<const float4*>(W + (size_t)row * NDIM);
  const float4* __restrict__ X = reinterpret_cast<const float4*>(x_i);

  float acc = 0.0f;
  // NDIM/4 float4 per row = 2048; /64 lanes = 32 iterations.
#pragma unroll 4
  for (int it = 0; it < (NDIM / 4) / 64; ++it) {
    const float4 w = Wrow[it * 64 + lane];
    const float4 x = X[it * 64 + lane];
    acc = fmaf(w.x, x.x, acc);
    acc = fmaf(w.y, x.y, acc);
    acc = fmaf(w.z, x.z, acc);
    acc = fmaf(w.w, x.w, acc);
  }

  // wave (64-lane) butterfly reduction
#pragma unroll
  for (int off = 32; off > 0; off >>= 1) acc += __shfl_xor(acc, off, 64);

  __shared__ float wsum[WAVES_PER_BLOCK];
  if (lane == 0) wsum[wave] = acc * (x_f[row] - x_i[row]);
  __syncthreads();

  if (threadIdx.x == 0) {
    const float block_sum = (wsum[0] + wsum[1]) + (wsum[2] + wsum[3]);
    atomicAdd(out, block_sum);  // relaxed, device-scope, no cache maintenance
  }
}

extern "C" void kernel_launch(void* const* d_in, const int* in_sizes, int n_in,
                              void* d_out, int out_size, void* d_ws, size_t ws_size,
                              hipStream_t stream) {
  const float* x_i = (const float*)d_in[0];
  const float* x_f = (const float*)d_in[1];
  const float* W   = (const float*)d_in[2];
  // d_in[3] = t (numerically unused), d_in[4] = arg (unused)

  float* out = (float*)d_out;

  // Rebuild the accumulator every call (poisoned once, never re-poisoned).
  hipMemsetAsync(out, 0, sizeof(float), stream);

  dyn_fused_kernel<<<BLOCKS, THREADS, 0, stream>>>(W, x_i, x_f, out);
}

// Round 4
// 46.994 us; speedup vs baseline: 3.5871x; 1.1554x over previous
//
#include <hip/hip_runtime.h>

// y = (x_f - x_i)^T (W @ x_i)  — scalar output.
// HBM/fabric-bound on W (256 MiB read once; ~half L3-resident across replays).
// Structure (R3 post-mortem): plain-store partials + tiny second kernel.
// Per-block atomics/fences are toxic on CDNA4 (R2: release/acquire per block
// = L2 maintenance storm, 6.7x; R3: same-address atomic convoy, +9 us).
// Main grid reorganized to 512 x 1024 (1 row/wave, 2 blocks/CU = full
// residency) so kernel 2 reduces only 512 partials with a single wave.

#define NDIM 8192
#define THREADS 1024
#define WAVES_PER_BLOCK 16
#define BLOCKS (NDIM / WAVES_PER_BLOCK)   // 512

__global__ __launch_bounds__(THREADS) void dyn_rowdot_kernel(
    const float* __restrict__ W,
    const float* __restrict__ x_i,
    const float* __restrict__ x_f,
    float* __restrict__ partial) {
  const int wave = threadIdx.x >> 6;   // 0..15
  const int lane = threadIdx.x & 63;
  const int row = blockIdx.x * WAVES_PER_BLOCK + wave;

  const float4* __restrict__ Wrow =
      reinterpret_cast<const float4*>(W + (size_t)row * NDIM);
  const float4* __restrict__ X = reinterpret_cast<const float4*>(x_i);

  float acc = 0.0f;
  // NDIM/4 float4 per row = 2048; /64 lanes = 32 iterations.
#pragma unroll 4
  for (int it = 0; it < (NDIM / 4) / 64; ++it) {
    const float4 w = Wrow[it * 64 + lane];
    const float4 x = X[it * 64 + lane];
    acc = fmaf(w.x, x.x, acc);
    acc = fmaf(w.y, x.y, acc);
    acc = fmaf(w.z, x.z, acc);
    acc = fmaf(w.w, x.w, acc);
  }

  // wave (64-lane) butterfly reduction
#pragma unroll
  for (int off = 32; off > 0; off >>= 1) acc += __shfl_xor(acc, off, 64);

  __shared__ float wsum[WAVES_PER_BLOCK];
  if (lane == 0) wsum[wave] = acc * (x_f[row] - x_i[row]);
  __syncthreads();

  // one wave tree-sums the 16 wave partials
  if (threadIdx.x < 64) {
    float b = (threadIdx.x < WAVES_PER_BLOCK) ? wsum[threadIdx.x] : 0.0f;
#pragma unroll
    for (int off = 8; off > 0; off >>= 1) b += __shfl_xor(b, off, 64);
    if (threadIdx.x == 0) partial[blockIdx.x] = b;
  }
}

// Single-wave final reduce: 512 floats = 2 float4 per lane, pure shuffles.
__global__ __launch_bounds__(64) void dyn_reduce_kernel(
    const float* __restrict__ partial, float* __restrict__ out) {
  const int lane = threadIdx.x;  // 0..63
  const float4* __restrict__ P = reinterpret_cast<const float4*>(partial);
  const float4 a = P[lane];
  const float4 b = P[lane + 64];
  float acc = ((a.x + a.y) + (a.z + a.w)) + ((b.x + b.y) + (b.z + b.w));
#pragma unroll
  for (int off = 32; off > 0; off >>= 1) acc += __shfl_xor(acc, off, 64);
  if (lane == 0) out[0] = acc;
}

extern "C" void kernel_launch(void* const* d_in, const int* in_sizes, int n_in,
                              void* d_out, int out_size, void* d_ws, size_t ws_size,
                              hipStream_t stream) {
  const float* x_i = (const float*)d_in[0];
  const float* x_f = (const float*)d_in[1];
  const float* W   = (const float*)d_in[2];
  // d_in[3] = t (numerically unused), d_in[4] = arg (unused)

  float* partial = (float*)d_ws;   // 512 * 4 B = 2 KiB of scratch
  float* out     = (float*)d_out;

  dyn_rowdot_kernel<<<BLOCKS, THREADS, 0, stream>>>(W, x_i, x_f, partial);
  dyn_reduce_kernel<<<1, 64, 0, stream>>>(partial, out);
}

// Round 5
// 44.786 us; speedup vs baseline: 3.7639x; 1.0493x over previous
//
#include <hip/hip_runtime.h>

// y = (x_f - x_i)^T (W @ x_i)  — scalar output.
// HBM/fabric-bound on W (256 MiB read once per call; ~half stays L3-resident
// across replays). One wave per row, float4 loads, plain-store partials +
// tiny second dispatch. This is the best measured structure (R1 = 45.4 us,
// main dispatch ~42.7 us = 97.6% of the 6.29 TB/s achievable ceiling):
//  - R2 (fused, per-block release/acquire): 288 us — L2 cache-maintenance storm.
//  - R3 (fused, relaxed atomicAdd + memset node): 54.3 us — atomic convoy.
//  - R4 (1024-thread blocks, 512 partials): 47.0 us — block completion-tail skew.
// Per-block coherence traffic during a streaming kernel costs more than a
// clean second dispatch on CDNA4.

#define NDIM 8192
#define THREADS 256
#define WAVES_PER_BLOCK 4
#define BLOCKS (NDIM / WAVES_PER_BLOCK)   // 2048

__global__ __launch_bounds__(THREADS) void dyn_rowdot_kernel(
    const float* __restrict__ W,
    const float* __restrict__ x_i,
    const float* __restrict__ x_f,
    float* __restrict__ partial) {
  const int wave = threadIdx.x >> 6;   // 0..3
  const int lane = threadIdx.x & 63;
  const int row = blockIdx.x * WAVES_PER_BLOCK + wave;

  const float4* __restrict__ Wrow =
      reinterpret_cast<const float4*>(W + (size_t)row * NDIM);
  const float4* __restrict__ X = reinterpret_cast<const float4*>(x_i);

  float acc = 0.0f;
  // NDIM/4 float4 per row = 2048; /64 lanes = 32 iterations.
#pragma unroll 4
  for (int it = 0; it < (NDIM / 4) / 64; ++it) {
    const float4 w = Wrow[it * 64 + lane];
    const float4 x = X[it * 64 + lane];
    acc = fmaf(w.x, x.x, acc);
    acc = fmaf(w.y, x.y, acc);
    acc = fmaf(w.z, x.z, acc);
    acc = fmaf(w.w, x.w, acc);
  }

  // wave (64-lane) butterfly reduction
#pragma unroll
  for (int off = 32; off > 0; off >>= 1) acc += __shfl_xor(acc, off, 64);

  __shared__ float wsum[WAVES_PER_BLOCK];
  if (lane == 0) wsum[wave] = acc * (x_f[row] - x_i[row]);
  __syncthreads();
  if (threadIdx.x == 0)
    partial[blockIdx.x] = (wsum[0] + wsum[1]) + (wsum[2] + wsum[3]);
}

__global__ __launch_bounds__(THREADS) void dyn_reduce_kernel(
    const float* __restrict__ partial, float* __restrict__ out) {
  float acc = 0.0f;
  for (int i = threadIdx.x; i < BLOCKS; i += THREADS) acc += partial[i];
#pragma unroll
  for (int off = 32; off > 0; off >>= 1) acc += __shfl_xor(acc, off, 64);
  __shared__ float wsum[WAVES_PER_BLOCK];
  const int wave = threadIdx.x >> 6;
  const int lane = threadIdx.x & 63;
  if (lane == 0) wsum[wave] = acc;
  __syncthreads();
  if (threadIdx.x == 0)
    out[0] = (wsum[0] + wsum[1]) + (wsum[2] + wsum[3]);
}

extern "C" void kernel_launch(void* const* d_in, const int* in_sizes, int n_in,
                              void* d_out, int out_size, void* d_ws, size_t ws_size,
                              hipStream_t stream) {
  const float* x_i = (const float*)d_in[0];
  const float* x_f = (const float*)d_in[1];
  const float* W   = (const float*)d_in[2];
  // d_in[3] = t (numerically unused), d_in[4] = arg (unused)

  float* partial = (float*)d_ws;        // needs BLOCKS*4 = 8 KiB of scratch
  float* out     = (float*)d_out;

  dyn_rowdot_kernel<<<BLOCKS, THREADS, 0, stream>>>(W, x_i, x_f, partial);
  dyn_reduce_kernel<<<1, THREADS, 0, stream>>>(partial, out);
}